// Round 1
// baseline (502.447 us; speedup 1.0000x reference)
//
#include <hip/hip_runtime.h>

typedef __attribute__((ext_vector_type(8))) short short8;
typedef __attribute__((ext_vector_type(4))) float f32x4;

#define NHEADS 16
#define DK 64
#define SEQ 2048
#define DMODEL 1024

__device__ __forceinline__ unsigned short f2bf(float f) {
  union { float f; unsigned int u; } c; c.f = f;
  unsigned int u = c.u;
  return (unsigned short)((u + 0x7FFFu + ((u >> 16) & 1u)) >> 16);
}

__device__ __forceinline__ short8 ldg16(const unsigned short* p) {
  return *reinterpret_cast<const short8*>(p);
}

__device__ __forceinline__ void gload_lds16(const unsigned short* g, unsigned short* l) {
  __builtin_amdgcn_global_load_lds(
      (const __attribute__((address_space(1))) unsigned int*)g,
      (__attribute__((address_space(3))) unsigned int*)l, 16, 0, 0);
}

__global__ void cast_f32_bf16(const float* __restrict__ src,
                              unsigned short* __restrict__ dst, int n4) {
  int i = blockIdx.x * blockDim.x + threadIdx.x;
  if (i >= n4) return;
  float4 v = reinterpret_cast<const float4*>(src)[i];
  ushort4 o;
  o.x = f2bf(v.x); o.y = f2bf(v.y); o.z = f2bf(v.z); o.w = f2bf(v.w);
  reinterpret_cast<ushort4*>(dst)[i] = o;
}

// ---- shared 128x128-tile GEMM core: C[m0:+128, n0:+128] = A[M,1024] * W[N,1024]^T
__device__ __forceinline__ void gemm_core(const unsigned short* __restrict__ A,
                                          const unsigned short* __restrict__ W,
                                          unsigned short* As, unsigned short* Bs,
                                          int m0, int n0, f32x4 acc[4][4]) {
  const int t = threadIdx.x;
  const int lane = t & 63, w = t >> 6;
  const int wr = w >> 1, wc = w & 1;
  const int srow = t >> 2, scol = (t & 3) * 8;
  const int lr = lane >> 4, lc = lane & 15;
  for (int k0 = 0; k0 < DMODEL; k0 += 32) {
    __syncthreads();
    gload_lds16(A + (size_t)(m0 + srow) * DMODEL + k0 + scol, As + w * 512);
    gload_lds16(A + (size_t)(m0 + 64 + srow) * DMODEL + k0 + scol, As + 2048 + w * 512);
    gload_lds16(W + (size_t)(n0 + srow) * DMODEL + k0 + scol, Bs + w * 512);
    gload_lds16(W + (size_t)(n0 + 64 + srow) * DMODEL + k0 + scol, Bs + 2048 + w * 512);
    __syncthreads();
    short8 a[4], b[4];
#pragma unroll
    for (int i = 0; i < 4; ++i) {
      a[i] = *reinterpret_cast<const short8*>(As + (wr * 64 + i * 16 + lc) * 32 + lr * 8);
      b[i] = *reinterpret_cast<const short8*>(Bs + (wc * 64 + i * 16 + lc) * 32 + lr * 8);
    }
#pragma unroll
    for (int mi = 0; mi < 4; ++mi)
#pragma unroll
      for (int ni = 0; ni < 4; ++ni)
        acc[mi][ni] = __builtin_amdgcn_mfma_f32_16x16x32_bf16(a[mi], b[ni], acc[mi][ni], 0, 0, 0);
  }
}

struct ProjPtrs {
  const unsigned short* A0; const unsigned short* A1; const unsigned short* A2;
  const unsigned short* W0; const unsigned short* W1; const unsigned short* W2;
  const float* bias0; const float* bias1; const float* bias2;
  unsigned short* dst0; unsigned short* dst1; unsigned short* dst2;
};

// z=0: Q (pre-scaled 1/8, [B,H,S,64]); z=1: K ([B,H,S,64]); z=2: V transposed ([B,H,64,S])
__global__ __launch_bounds__(256) void gemm_proj(ProjPtrs p) {
  __shared__ __align__(16) unsigned short As[4096];
  __shared__ __align__(16) unsigned short Bs[4096];
  const int mode = blockIdx.z;
  const unsigned short* A = mode == 0 ? p.A0 : (mode == 1 ? p.A1 : p.A2);
  const unsigned short* W = mode == 0 ? p.W0 : (mode == 1 ? p.W1 : p.W2);
  const float* bias = mode == 0 ? p.bias0 : (mode == 1 ? p.bias1 : p.bias2);
  unsigned short* dst = mode == 0 ? p.dst0 : (mode == 1 ? p.dst1 : p.dst2);
  const int m0 = blockIdx.y * 128, n0 = blockIdx.x * 128;
  f32x4 acc[4][4] = {};
  gemm_core(A, W, As, Bs, m0, n0, acc);
  const int lane = threadIdx.x & 63, w = threadIdx.x >> 6;
  const int wr = w >> 1, wc = w & 1;
  const int lr = lane >> 4, lc = lane & 15;
#pragma unroll
  for (int mi = 0; mi < 4; ++mi) {
#pragma unroll
    for (int ni = 0; ni < 4; ++ni) {
      const int cg = n0 + wc * 64 + ni * 16 + lc;
      const int rb = m0 + wr * 64 + mi * 16 + lr * 4;
      const float bv = bias[cg];
      const int h = cg >> 6, d = cg & 63;
      if (mode == 2) {
        const int bb = rb >> 11, s = rb & 2047;
        ushort4 pk;
        pk.x = f2bf(acc[mi][ni][0] + bv);
        pk.y = f2bf(acc[mi][ni][1] + bv);
        pk.z = f2bf(acc[mi][ni][2] + bv);
        pk.w = f2bf(acc[mi][ni][3] + bv);
        *reinterpret_cast<ushort4*>(dst + (((size_t)((bb * NHEADS + h) * DK + d)) << 11) + s) = pk;
      } else {
        const float sc = (mode == 0) ? 0.125f : 1.0f;
#pragma unroll
        for (int j = 0; j < 4; ++j) {
          const int rg = rb + j;
          const int bb = rg >> 11, s = rg & 2047;
          dst[((size_t)(bb * NHEADS + h) * SEQ + s) * DK + d] = f2bf((acc[mi][ni][j] + bv) * sc);
        }
      }
    }
  }
}

__global__ __launch_bounds__(256) void gemm_out(const unsigned short* __restrict__ A,
                                                const unsigned short* __restrict__ W,
                                                const float* __restrict__ bias,
                                                float* __restrict__ out) {
  __shared__ __align__(16) unsigned short As[4096];
  __shared__ __align__(16) unsigned short Bs[4096];
  const int m0 = blockIdx.y * 128, n0 = blockIdx.x * 128;
  f32x4 acc[4][4] = {};
  gemm_core(A, W, As, Bs, m0, n0, acc);
  const int lane = threadIdx.x & 63, w = threadIdx.x >> 6;
  const int wr = w >> 1, wc = w & 1;
  const int lr = lane >> 4, lc = lane & 15;
#pragma unroll
  for (int mi = 0; mi < 4; ++mi)
#pragma unroll
    for (int ni = 0; ni < 4; ++ni) {
      const int cg = n0 + wc * 64 + ni * 16 + lc;
      const int rb = m0 + wr * 64 + mi * 16 + lr * 4;
      const float bv = bias[cg];
#pragma unroll
      for (int j = 0; j < 4; ++j)
        out[(size_t)(rb + j) * DMODEL + cg] = acc[mi][ni][j] + bv;
    }
}

// Flash attention: 1 block = 4 waves, each wave owns 16 q-rows of one (b,h).
__global__ __launch_bounds__(256) void attn_fwd(const unsigned short* __restrict__ Qh,
                                                const unsigned short* __restrict__ Kh,
                                                const unsigned short* __restrict__ Vt,
                                                unsigned short* __restrict__ Oh) {
  __shared__ __align__(16) unsigned short P[4][16][72];  // per-wave P tile, padded stride
  const int t = threadIdx.x, w = t >> 6, lane = t & 63;
  const int bx = blockIdx.x;
  const int bh = bx >> 5, qblk = bx & 31;
  const int q0 = qblk * 64 + w * 16;
  const unsigned short* Qp = Qh + (size_t)bh * SEQ * DK;
  const unsigned short* Kp = Kh + (size_t)bh * SEQ * DK;
  const unsigned short* Vp = Vt + (size_t)bh * DK * SEQ;
  const int r = lane & 15, g = lane >> 4;

  const short8 qf0 = ldg16(Qp + (size_t)(q0 + r) * DK + g * 8);
  const short8 qf1 = ldg16(Qp + (size_t)(q0 + r) * DK + 32 + g * 8);

  float m_run[4], l_run[4];
  f32x4 o[4] = {};
#pragma unroll
  for (int j = 0; j < 4; ++j) { m_run[j] = -1e30f; l_run[j] = 0.f; }

  for (int kv0 = 0; kv0 < SEQ; kv0 += 64) {
    f32x4 s[4] = {};
#pragma unroll
    for (int nt = 0; nt < 4; ++nt) {
      short8 kf0 = ldg16(Kp + (size_t)(kv0 + nt * 16 + r) * DK + g * 8);
      short8 kf1 = ldg16(Kp + (size_t)(kv0 + nt * 16 + r) * DK + 32 + g * 8);
      s[nt] = __builtin_amdgcn_mfma_f32_16x16x32_bf16(qf0, kf0, s[nt], 0, 0, 0);
      s[nt] = __builtin_amdgcn_mfma_f32_16x16x32_bf16(qf1, kf1, s[nt], 0, 0, 0);
    }
    // online softmax: score row = g*4+j lives in 16-lane group g, reg j
    float al[4];
#pragma unroll
    for (int j = 0; j < 4; ++j) {
      float mx = fmaxf(fmaxf(s[0][j], s[1][j]), fmaxf(s[2][j], s[3][j]));
#pragma unroll
      for (int dlt = 1; dlt < 16; dlt <<= 1) mx = fmaxf(mx, __shfl_xor(mx, dlt, 16));
      const float mn = fmaxf(m_run[j], mx);
      al[j] = __expf(m_run[j] - mn);
      float sum = 0.f;
#pragma unroll
      for (int nt = 0; nt < 4; ++nt) {
        const float pv = __expf(s[nt][j] - mn);
        s[nt][j] = pv; sum += pv;
      }
#pragma unroll
      for (int dlt = 1; dlt < 16; dlt <<= 1) sum += __shfl_xor(sum, dlt, 16);
      l_run[j] = l_run[j] * al[j] + sum;
      m_run[j] = mn;
    }
#pragma unroll
    for (int nt = 0; nt < 4; ++nt) {
#pragma unroll
      for (int j = 0; j < 4; ++j) {
        P[w][g * 4 + j][nt * 16 + r] = f2bf(s[nt][j]);
        o[nt][j] *= al[j];
      }
    }
    __syncthreads();
    const short8 pf0 = *reinterpret_cast<const short8*>(&P[w][r][g * 8]);
    const short8 pf1 = *reinterpret_cast<const short8*>(&P[w][r][32 + g * 8]);
#pragma unroll
    for (int nt = 0; nt < 4; ++nt) {
      short8 vf0 = ldg16(Vp + (size_t)(nt * 16 + r) * SEQ + kv0 + g * 8);
      short8 vf1 = ldg16(Vp + (size_t)(nt * 16 + r) * SEQ + kv0 + 32 + g * 8);
      o[nt] = __builtin_amdgcn_mfma_f32_16x16x32_bf16(pf0, vf0, o[nt], 0, 0, 0);
      o[nt] = __builtin_amdgcn_mfma_f32_16x16x32_bf16(pf1, vf1, o[nt], 0, 0, 0);
    }
  }

  float inv[4];
#pragma unroll
  for (int j = 0; j < 4; ++j) inv[j] = 1.f / l_run[j];
  const size_t ob = ((size_t)((bh >> 4) * SEQ + q0)) * DMODEL + (size_t)(bh & 15) * DK;
#pragma unroll
  for (int nt = 0; nt < 4; ++nt)
#pragma unroll
    for (int j = 0; j < 4; ++j)
      Oh[ob + (size_t)(g * 4 + j) * DMODEL + nt * 16 + r] = f2bf(o[nt][j] * inv[j]);
}

extern "C" void kernel_launch(void* const* d_in, const int* in_sizes, int n_in,
                              void* d_out, int out_size, void* d_ws, size_t ws_size,
                              hipStream_t stream) {
  const float* q   = (const float*)d_in[0];
  const float* k   = (const float*)d_in[1];
  const float* v   = (const float*)d_in[2];
  const float* w_q = (const float*)d_in[3];
  const float* b_q = (const float*)d_in[4];
  const float* w_k = (const float*)d_in[5];
  const float* b_k = (const float*)d_in[6];
  const float* w_v = (const float*)d_in[7];
  const float* b_v = (const float*)d_in[8];
  const float* w_o = (const float*)d_in[9];
  const float* b_o = (const float*)d_in[10];
  float* out = (float*)d_out;
  char* ws = (char*)d_ws;
  const size_t MB = (size_t)1 << 20;
  unsigned short* qc  = (unsigned short*)(ws + 0 * MB);
  unsigned short* kc  = (unsigned short*)(ws + 8 * MB);
  unsigned short* vc  = (unsigned short*)(ws + 16 * MB);
  unsigned short* wqc = (unsigned short*)(ws + 24 * MB);
  unsigned short* wkc = (unsigned short*)(ws + 26 * MB);
  unsigned short* wvc = (unsigned short*)(ws + 28 * MB);
  unsigned short* woc = (unsigned short*)(ws + 30 * MB);
  unsigned short* Qh  = (unsigned short*)(ws + 32 * MB);
  unsigned short* Kh  = (unsigned short*)(ws + 40 * MB);
  unsigned short* Vt  = (unsigned short*)(ws + 48 * MB);
  unsigned short* Oh  = (unsigned short*)(ws + 56 * MB);

  cast_f32_bf16<<<4096, 256, 0, stream>>>(q, qc, 1048576);
  cast_f32_bf16<<<4096, 256, 0, stream>>>(k, kc, 1048576);
  cast_f32_bf16<<<4096, 256, 0, stream>>>(v, vc, 1048576);
  cast_f32_bf16<<<1024, 256, 0, stream>>>(w_q, wqc, 262144);
  cast_f32_bf16<<<1024, 256, 0, stream>>>(w_k, wkc, 262144);
  cast_f32_bf16<<<1024, 256, 0, stream>>>(w_v, wvc, 262144);
  cast_f32_bf16<<<1024, 256, 0, stream>>>(w_o, woc, 262144);

  ProjPtrs p;
  p.A0 = qc; p.A1 = kc; p.A2 = vc;
  p.W0 = wqc; p.W1 = wkc; p.W2 = wvc;
  p.bias0 = b_q; p.bias1 = b_k; p.bias2 = b_v;
  p.dst0 = Qh; p.dst1 = Kh; p.dst2 = Vt;
  gemm_proj<<<dim3(8, 32, 3), 256, 0, stream>>>(p);

  attn_fwd<<<1024, 256, 0, stream>>>(Qh, Kh, Vt, Oh);

  gemm_out<<<dim3(8, 32), 256, 0, stream>>>(Oh, woc, b_o, out);
}

// Round 3
// 407.789 us; speedup vs baseline: 1.2321x; 1.2321x over previous
//
#include <hip/hip_runtime.h>

typedef __attribute__((ext_vector_type(8))) short short8;
typedef __attribute__((ext_vector_type(4))) float f32x4;

#define NHEADS 16
#define DK 64
#define SEQ 2048
#define DMODEL 1024

__device__ __forceinline__ unsigned short f2bf(float f) {
  union { float f; unsigned int u; } c; c.f = f;
  unsigned int u = c.u;
  return (unsigned short)((u + 0x7FFFu + ((u >> 16) & 1u)) >> 16);
}

__device__ __forceinline__ short8 ldg16(const unsigned short* p) {
  return *reinterpret_cast<const short8*>(p);
}

__device__ __forceinline__ void gload_lds16(const unsigned short* g, unsigned short* l) {
  __builtin_amdgcn_global_load_lds(
      (const __attribute__((address_space(1))) unsigned int*)g,
      (__attribute__((address_space(3))) unsigned int*)l, 16, 0, 0);
}

__global__ void cast_qkv(const float* __restrict__ a0, const float* __restrict__ a1,
                         const float* __restrict__ a2, unsigned short* __restrict__ d0,
                         unsigned short* __restrict__ d1, unsigned short* __restrict__ d2) {
  const float* s = blockIdx.y == 0 ? a0 : (blockIdx.y == 1 ? a1 : a2);
  unsigned short* d = blockIdx.y == 0 ? d0 : (blockIdx.y == 1 ? d1 : d2);
  int i = blockIdx.x * blockDim.x + threadIdx.x;
  float4 v = reinterpret_cast<const float4*>(s)[i];
  ushort4 o;
  o.x = f2bf(v.x); o.y = f2bf(v.y); o.z = f2bf(v.z); o.w = f2bf(v.w);
  reinterpret_cast<ushort4*>(d)[i] = o;
}

__global__ void cast_w4(const float* __restrict__ a0, const float* __restrict__ a1,
                        const float* __restrict__ a2, const float* __restrict__ a3,
                        unsigned short* __restrict__ d0, unsigned short* __restrict__ d1,
                        unsigned short* __restrict__ d2, unsigned short* __restrict__ d3) {
  const float* s = blockIdx.y == 0 ? a0 : (blockIdx.y == 1 ? a1 : (blockIdx.y == 2 ? a2 : a3));
  unsigned short* d = blockIdx.y == 0 ? d0 : (blockIdx.y == 1 ? d1 : (blockIdx.y == 2 ? d2 : d3));
  int i = blockIdx.x * blockDim.x + threadIdx.x;
  float4 v = reinterpret_cast<const float4*>(s)[i];
  ushort4 o;
  o.x = f2bf(v.x); o.y = f2bf(v.y); o.z = f2bf(v.z); o.w = f2bf(v.w);
  reinterpret_cast<ushort4*>(d)[i] = o;
}

// ---- 128x128-tile GEMM core, 8 waves (512 thr), wave tile 64x32.
// C[m0:+128, n0:+128] = A[M,1024] * W[N,1024]^T
__device__ __forceinline__ void gemm_core(const unsigned short* __restrict__ A,
                                          const unsigned short* __restrict__ W,
                                          unsigned short* As, unsigned short* Bs,
                                          int m0, int n0, f32x4 acc[4][2]) {
  const int t = threadIdx.x;
  const int lane = t & 63, w = t >> 6;
  const int wr = w >> 2, wc = w & 3;
  const int srow = t >> 2, scol = (t & 3) * 8;
  const int lr = lane >> 4, lc = lane & 15;
  for (int k0 = 0; k0 < DMODEL; k0 += 32) {
    __syncthreads();
    gload_lds16(A + (size_t)(m0 + srow) * DMODEL + k0 + scol, As + w * 512);
    gload_lds16(W + (size_t)(n0 + srow) * DMODEL + k0 + scol, Bs + w * 512);
    __syncthreads();
    short8 a[4], b[2];
#pragma unroll
    for (int i = 0; i < 4; ++i)
      a[i] = *reinterpret_cast<const short8*>(As + (wr * 64 + i * 16 + lc) * 32 + lr * 8);
#pragma unroll
    for (int i = 0; i < 2; ++i)
      b[i] = *reinterpret_cast<const short8*>(Bs + (wc * 32 + i * 16 + lc) * 32 + lr * 8);
#pragma unroll
    for (int mi = 0; mi < 4; ++mi)
#pragma unroll
      for (int ni = 0; ni < 2; ++ni)
        acc[mi][ni] = __builtin_amdgcn_mfma_f32_16x16x32_bf16(a[mi], b[ni], acc[mi][ni], 0, 0, 0);
  }
}

struct ProjPtrs {
  const unsigned short* A0; const unsigned short* A1; const unsigned short* A2;
  const unsigned short* W0; const unsigned short* W1; const unsigned short* W2;
  const float* bias0; const float* bias1; const float* bias2;
  unsigned short* dst0; unsigned short* dst1; unsigned short* dst2;
};

// z=0: Q (pre-scaled 1/8, [B,H,S,64]); z=1: K ([B,H,S,64]); z=2: V transposed ([B,H,64,S])
__global__ __launch_bounds__(512) void gemm_proj(ProjPtrs p) {
  __shared__ __align__(16) unsigned short As[4096];
  __shared__ __align__(16) unsigned short Bs[4096];
  const int mode = blockIdx.z;
  const unsigned short* A = mode == 0 ? p.A0 : (mode == 1 ? p.A1 : p.A2);
  const unsigned short* W = mode == 0 ? p.W0 : (mode == 1 ? p.W1 : p.W2);
  const float* bias = mode == 0 ? p.bias0 : (mode == 1 ? p.bias1 : p.bias2);
  unsigned short* dst = mode == 0 ? p.dst0 : (mode == 1 ? p.dst1 : p.dst2);
  const int m0 = blockIdx.y * 128, n0 = blockIdx.x * 128;
  f32x4 acc[4][2] = {};
  gemm_core(A, W, As, Bs, m0, n0, acc);
  const int lane = threadIdx.x & 63, w = threadIdx.x >> 6;
  const int wr = w >> 2, wc = w & 3;
  const int lr = lane >> 4, lc = lane & 15;
#pragma unroll
  for (int mi = 0; mi < 4; ++mi) {
#pragma unroll
    for (int ni = 0; ni < 2; ++ni) {
      const int cg = n0 + wc * 32 + ni * 16 + lc;
      const int rb = m0 + wr * 64 + mi * 16 + lr * 4;
      const float bv = bias[cg];
      const int h = cg >> 6, d = cg & 63;
      if (mode == 2) {
        const int bb = rb >> 11, s = rb & 2047;
        ushort4 pk;
        pk.x = f2bf(acc[mi][ni][0] + bv);
        pk.y = f2bf(acc[mi][ni][1] + bv);
        pk.z = f2bf(acc[mi][ni][2] + bv);
        pk.w = f2bf(acc[mi][ni][3] + bv);
        *reinterpret_cast<ushort4*>(dst + (((size_t)((bb * NHEADS + h) * DK + d)) << 11) + s) = pk;
      } else {
        const float sc = (mode == 0) ? 0.125f : 1.0f;
#pragma unroll
        for (int j = 0; j < 4; ++j) {
          const int rg = rb + j;
          const int bb = rg >> 11, s = rg & 2047;
          dst[((size_t)(bb * NHEADS + h) * SEQ + s) * DK + d] = f2bf((acc[mi][ni][j] + bv) * sc);
        }
      }
    }
  }
}

__global__ __launch_bounds__(512) void gemm_out(const unsigned short* __restrict__ A,
                                                const unsigned short* __restrict__ W,
                                                const float* __restrict__ bias,
                                                float* __restrict__ out) {
  __shared__ __align__(16) unsigned short As[4096];
  __shared__ __align__(16) unsigned short Bs[4096];
  const int m0 = blockIdx.y * 128, n0 = blockIdx.x * 128;
  f32x4 acc[4][2] = {};
  gemm_core(A, W, As, Bs, m0, n0, acc);
  const int lane = threadIdx.x & 63, w = threadIdx.x >> 6;
  const int wr = w >> 2, wc = w & 3;
  const int lr = lane >> 4, lc = lane & 15;
#pragma unroll
  for (int mi = 0; mi < 4; ++mi)
#pragma unroll
    for (int ni = 0; ni < 2; ++ni) {
      const int cg = n0 + wc * 32 + ni * 16 + lc;
      const int rb = m0 + wr * 64 + mi * 16 + lr * 4;
      const float bv = bias[cg];
#pragma unroll
      for (int j = 0; j < 4; ++j)
        out[(size_t)(rb + j) * DMODEL + cg] = acc[mi][ni][j] + bv;
    }
}

// Flash attention, swapped QK^T: per-lane q-row softmax, per-wave P tile, no block barrier.
__global__ __launch_bounds__(256) void attn_fwd(const unsigned short* __restrict__ Qh,
                                                const unsigned short* __restrict__ Kh,
                                                const unsigned short* __restrict__ Vt,
                                                unsigned short* __restrict__ Oh) {
  __shared__ __align__(16) unsigned short P[4][16][72];  // per-wave [q][kv], padded
  const int t = threadIdx.x, w = t >> 6, lane = t & 63;
  const int bx = blockIdx.x;
  const int bh = bx >> 5, qblk = bx & 31;
  const int q0 = qblk * 64 + w * 16;
  const unsigned short* Qp = Qh + (size_t)bh * SEQ * DK;
  const unsigned short* Kp = Kh + (size_t)bh * SEQ * DK;
  const unsigned short* Vp = Vt + (size_t)bh * DK * SEQ;
  const int r = lane & 15, g = lane >> 4;

  // Q as B-operand: lane holds Q[q0+r][8g..8g+7] per k-half
  const short8 qf0 = ldg16(Qp + (size_t)(q0 + r) * DK + g * 8);
  const short8 qf1 = ldg16(Qp + (size_t)(q0 + r) * DK + 32 + g * 8);

  float m_run = -1e30f, l_run = 0.f;
  f32x4 o[4] = {};

  // K prefetch (A-operand frags) for kv0=0
  short8 kc0[4], kc1[4];
#pragma unroll
  for (int nt = 0; nt < 4; ++nt) {
    kc0[nt] = ldg16(Kp + (size_t)(nt * 16 + r) * DK + g * 8);
    kc1[nt] = ldg16(Kp + (size_t)(nt * 16 + r) * DK + 32 + g * 8);
  }

  for (int kv0 = 0; kv0 < SEQ; kv0 += 64) {
    // V loads for this tile (consumed after softmax)
    short8 vf0[4], vf1[4];
#pragma unroll
    for (int nt = 0; nt < 4; ++nt) {
      vf0[nt] = ldg16(Vp + (size_t)(nt * 16 + r) * SEQ + kv0 + g * 8);
      vf1[nt] = ldg16(Vp + (size_t)(nt * 16 + r) * SEQ + kv0 + 32 + g * 8);
    }
    // K prefetch for next tile
    const int kvn = (kv0 + 64) & (SEQ - 1);
    short8 kn0[4], kn1[4];
#pragma unroll
    for (int nt = 0; nt < 4; ++nt) {
      kn0[nt] = ldg16(Kp + (size_t)(kvn + nt * 16 + r) * DK + g * 8);
      kn1[nt] = ldg16(Kp + (size_t)(kvn + nt * 16 + r) * DK + 32 + g * 8);
    }
    // QK^T swapped: D[kv][q], lane holds q=r, kv=16nt+4g+j
    f32x4 s[4] = {};
#pragma unroll
    for (int nt = 0; nt < 4; ++nt) {
      s[nt] = __builtin_amdgcn_mfma_f32_16x16x32_bf16(kc0[nt], qf0, s[nt], 0, 0, 0);
      s[nt] = __builtin_amdgcn_mfma_f32_16x16x32_bf16(kc1[nt], qf1, s[nt], 0, 0, 0);
    }
    // per-lane row softmax (row q=r spread over 4 g-lanes)
    float pmax = fmaxf(fmaxf(s[0][0], s[0][1]), fmaxf(s[0][2], s[0][3]));
#pragma unroll
    for (int nt = 1; nt < 4; ++nt)
      pmax = fmaxf(pmax, fmaxf(fmaxf(s[nt][0], s[nt][1]), fmaxf(s[nt][2], s[nt][3])));
    pmax = fmaxf(pmax, __shfl_xor(pmax, 16));
    pmax = fmaxf(pmax, __shfl_xor(pmax, 32));
    const float mn = fmaxf(m_run, pmax);
    const float al = __expf(m_run - mn);
    float sum = 0.f;
#pragma unroll
    for (int nt = 0; nt < 4; ++nt)
#pragma unroll
      for (int j = 0; j < 4; ++j) {
        const float pv = __expf(s[nt][j] - mn);
        s[nt][j] = pv; sum += pv;
      }
    sum += __shfl_xor(sum, 16);
    sum += __shfl_xor(sum, 32);
    l_run = l_run * al + sum;
    m_run = mn;
    // P[q][kv] for PV A-operand
#pragma unroll
    for (int nt = 0; nt < 4; ++nt)
#pragma unroll
      for (int j = 0; j < 4; ++j)
        P[w][r][nt * 16 + g * 4 + j] = f2bf(s[nt][j]);
    asm volatile("s_waitcnt lgkmcnt(0)" ::: "memory");
    __builtin_amdgcn_sched_barrier(0);
    const short8 pf0 = *reinterpret_cast<const short8*>(&P[w][r][g * 8]);
    const short8 pf1 = *reinterpret_cast<const short8*>(&P[w][r][32 + g * 8]);
    // rescale O (rows q=4g+j) with per-row alpha fetched from lane 4g+j
    float alj[4];
#pragma unroll
    for (int j = 0; j < 4; ++j) alj[j] = __shfl(al, 4 * g + j, 16);
#pragma unroll
    for (int nt = 0; nt < 4; ++nt)
#pragma unroll
      for (int j = 0; j < 4; ++j) o[nt][j] *= alj[j];
#pragma unroll
    for (int nt = 0; nt < 4; ++nt) {
      o[nt] = __builtin_amdgcn_mfma_f32_16x16x32_bf16(pf0, vf0[nt], o[nt], 0, 0, 0);
      o[nt] = __builtin_amdgcn_mfma_f32_16x16x32_bf16(pf1, vf1[nt], o[nt], 0, 0, 0);
    }
#pragma unroll
    for (int nt = 0; nt < 4; ++nt) { kc0[nt] = kn0[nt]; kc1[nt] = kn1[nt]; }
  }

  const float inv = 1.f / l_run;
  float invj[4];
#pragma unroll
  for (int j = 0; j < 4; ++j) invj[j] = __shfl(inv, 4 * g + j, 16);
  const size_t ob = ((size_t)((bh >> 4) * SEQ + q0)) * DMODEL + (size_t)(bh & 15) * DK;
#pragma unroll
  for (int nt = 0; nt < 4; ++nt)
#pragma unroll
    for (int j = 0; j < 4; ++j)
      Oh[ob + (size_t)(g * 4 + j) * DMODEL + nt * 16 + r] = f2bf(o[nt][j] * invj[j]);
}

extern "C" void kernel_launch(void* const* d_in, const int* in_sizes, int n_in,
                              void* d_out, int out_size, void* d_ws, size_t ws_size,
                              hipStream_t stream) {
  const float* q   = (const float*)d_in[0];
  const float* k   = (const float*)d_in[1];
  const float* v   = (const float*)d_in[2];
  const float* w_q = (const float*)d_in[3];
  const float* b_q = (const float*)d_in[4];
  const float* w_k = (const float*)d_in[5];
  const float* b_k = (const float*)d_in[6];
  const float* w_v = (const float*)d_in[7];
  const float* b_v = (const float*)d_in[8];
  const float* w_o = (const float*)d_in[9];
  const float* b_o = (const float*)d_in[10];
  float* out = (float*)d_out;
  char* ws = (char*)d_ws;
  const size_t MB = (size_t)1 << 20;
  unsigned short* qc  = (unsigned short*)(ws + 0 * MB);
  unsigned short* kc  = (unsigned short*)(ws + 8 * MB);
  unsigned short* vc  = (unsigned short*)(ws + 16 * MB);
  unsigned short* wqc = (unsigned short*)(ws + 24 * MB);
  unsigned short* wkc = (unsigned short*)(ws + 26 * MB);
  unsigned short* wvc = (unsigned short*)(ws + 28 * MB);
  unsigned short* woc = (unsigned short*)(ws + 30 * MB);
  unsigned short* Qh  = (unsigned short*)(ws + 32 * MB);
  unsigned short* Kh  = (unsigned short*)(ws + 40 * MB);
  unsigned short* Vt  = (unsigned short*)(ws + 48 * MB);
  unsigned short* Oh  = (unsigned short*)(ws + 56 * MB);

  cast_qkv<<<dim3(4096, 3), 256, 0, stream>>>(q, k, v, qc, kc, vc);
  cast_w4<<<dim3(1024, 4), 256, 0, stream>>>(w_q, w_k, w_v, w_o, wqc, wkc, wvc, woc);

  ProjPtrs p;
  p.A0 = qc; p.A1 = kc; p.A2 = vc;
  p.W0 = wqc; p.W1 = wkc; p.W2 = wvc;
  p.bias0 = b_q; p.bias1 = b_k; p.bias2 = b_v;
  p.dst0 = Qh; p.dst1 = Kh; p.dst2 = Vt;
  gemm_proj<<<dim3(8, 32, 3), 512, 0, stream>>>(p);

  attn_fwd<<<1024, 256, 0, stream>>>(Qh, Kh, Vt, Oh);

  gemm_out<<<dim3(8, 32), 512, 0, stream>>>(Oh, woc, b_o, out);
}

// Round 4
// 406.749 us; speedup vs baseline: 1.2353x; 1.0026x over previous
//
#include <hip/hip_runtime.h>

typedef __attribute__((ext_vector_type(8))) short short8;
typedef __attribute__((ext_vector_type(4))) float f32x4;

#define NHEADS 16
#define DK 64
#define SEQ 2048
#define DMODEL 1024

__device__ __forceinline__ unsigned short f2bf(float f) {
  union { float f; unsigned int u; } c; c.f = f;
  unsigned int u = c.u;
  return (unsigned short)((u + 0x7FFFu + ((u >> 16) & 1u)) >> 16);
}

__device__ __forceinline__ float exp2_hw(float x) {
  float y;
  asm("v_exp_f32 %0, %1" : "=v"(y) : "v"(x));
  return y;
}

__device__ __forceinline__ unsigned int cvtpk_bf16(float lo, float hi) {
  unsigned int r;
  asm("v_cvt_pk_bf16_f32 %0, %1, %2" : "=v"(r) : "v"(lo), "v"(hi));
  return r;
}

__device__ __forceinline__ short8 ldg16(const unsigned short* p) {
  return *reinterpret_cast<const short8*>(p);
}

__device__ __forceinline__ void gload_lds16(const unsigned short* g, unsigned short* l) {
  __builtin_amdgcn_global_load_lds(
      (const __attribute__((address_space(1))) unsigned int*)g,
      (__attribute__((address_space(3))) unsigned int*)l, 16, 0, 0);
}

__global__ void cast_qkv(const float* __restrict__ a0, const float* __restrict__ a1,
                         const float* __restrict__ a2, unsigned short* __restrict__ d0,
                         unsigned short* __restrict__ d1, unsigned short* __restrict__ d2) {
  const float* s = blockIdx.y == 0 ? a0 : (blockIdx.y == 1 ? a1 : a2);
  unsigned short* d = blockIdx.y == 0 ? d0 : (blockIdx.y == 1 ? d1 : d2);
  int i = blockIdx.x * blockDim.x + threadIdx.x;
  float4 v = reinterpret_cast<const float4*>(s)[i];
  ushort4 o;
  o.x = f2bf(v.x); o.y = f2bf(v.y); o.z = f2bf(v.z); o.w = f2bf(v.w);
  reinterpret_cast<ushort4*>(d)[i] = o;
}

__global__ void cast_w4(const float* __restrict__ a0, const float* __restrict__ a1,
                        const float* __restrict__ a2, const float* __restrict__ a3,
                        unsigned short* __restrict__ d0, unsigned short* __restrict__ d1,
                        unsigned short* __restrict__ d2, unsigned short* __restrict__ d3) {
  const float* s = blockIdx.y == 0 ? a0 : (blockIdx.y == 1 ? a1 : (blockIdx.y == 2 ? a2 : a3));
  unsigned short* d = blockIdx.y == 0 ? d0 : (blockIdx.y == 1 ? d1 : (blockIdx.y == 2 ? d2 : d3));
  int i = blockIdx.x * blockDim.x + threadIdx.x;
  float4 v = reinterpret_cast<const float4*>(s)[i];
  ushort4 o;
  o.x = f2bf(v.x); o.y = f2bf(v.y); o.z = f2bf(v.z); o.w = f2bf(v.w);
  reinterpret_cast<ushort4*>(d)[i] = o;
}

// ---- 128x128-tile GEMM core, 8 waves (512 thr), wave tile 64x32.
__device__ __forceinline__ void gemm_core(const unsigned short* __restrict__ A,
                                          const unsigned short* __restrict__ W,
                                          unsigned short* As, unsigned short* Bs,
                                          int m0, int n0, f32x4 acc[4][2]) {
  const int t = threadIdx.x;
  const int lane = t & 63, w = t >> 6;
  const int wr = w >> 2, wc = w & 3;
  const int srow = t >> 2, scol = (t & 3) * 8;
  const int lr = lane >> 4, lc = lane & 15;
  for (int k0 = 0; k0 < DMODEL; k0 += 32) {
    __syncthreads();
    gload_lds16(A + (size_t)(m0 + srow) * DMODEL + k0 + scol, As + w * 512);
    gload_lds16(W + (size_t)(n0 + srow) * DMODEL + k0 + scol, Bs + w * 512);
    __syncthreads();
    short8 a[4], b[2];
#pragma unroll
    for (int i = 0; i < 4; ++i)
      a[i] = *reinterpret_cast<const short8*>(As + (wr * 64 + i * 16 + lc) * 32 + lr * 8);
#pragma unroll
    for (int i = 0; i < 2; ++i)
      b[i] = *reinterpret_cast<const short8*>(Bs + (wc * 32 + i * 16 + lc) * 32 + lr * 8);
#pragma unroll
    for (int mi = 0; mi < 4; ++mi)
#pragma unroll
      for (int ni = 0; ni < 2; ++ni)
        acc[mi][ni] = __builtin_amdgcn_mfma_f32_16x16x32_bf16(a[mi], b[ni], acc[mi][ni], 0, 0, 0);
  }
}

struct ProjPtrs {
  const unsigned short* A0; const unsigned short* A1; const unsigned short* A2;
  const unsigned short* W0; const unsigned short* W1; const unsigned short* W2;
  const float* bias0; const float* bias1; const float* bias2;
  unsigned short* dst0; unsigned short* dst1; unsigned short* dst2;
};

// z=0: Q (pre-scaled 1/8*log2e, [B,H,S,64]); z=1: K; z=2: V transposed ([B,H,64,S])
__global__ __launch_bounds__(512) void gemm_proj(ProjPtrs p) {
  __shared__ __align__(16) unsigned short As[4096];
  __shared__ __align__(16) unsigned short Bs[4096];
  const int mode = blockIdx.z;
  const unsigned short* A = mode == 0 ? p.A0 : (mode == 1 ? p.A1 : p.A2);
  const unsigned short* W = mode == 0 ? p.W0 : (mode == 1 ? p.W1 : p.W2);
  const float* bias = mode == 0 ? p.bias0 : (mode == 1 ? p.bias1 : p.bias2);
  unsigned short* dst = mode == 0 ? p.dst0 : (mode == 1 ? p.dst1 : p.dst2);
  const int m0 = blockIdx.y * 128, n0 = blockIdx.x * 128;
  f32x4 acc[4][2] = {};
  gemm_core(A, W, As, Bs, m0, n0, acc);
  const int lane = threadIdx.x & 63, w = threadIdx.x >> 6;
  const int wr = w >> 2, wc = w & 3;
  const int lr = lane >> 4, lc = lane & 15;
#pragma unroll
  for (int mi = 0; mi < 4; ++mi) {
#pragma unroll
    for (int ni = 0; ni < 2; ++ni) {
      const int cg = n0 + wc * 32 + ni * 16 + lc;
      const int rb = m0 + wr * 64 + mi * 16 + lr * 4;
      const float bv = bias[cg];
      const int h = cg >> 6, d = cg & 63;
      if (mode == 2) {
        const int bb = rb >> 11, s = rb & 2047;
        ushort4 pk;
        pk.x = f2bf(acc[mi][ni][0] + bv);
        pk.y = f2bf(acc[mi][ni][1] + bv);
        pk.z = f2bf(acc[mi][ni][2] + bv);
        pk.w = f2bf(acc[mi][ni][3] + bv);
        *reinterpret_cast<ushort4*>(dst + (((size_t)((bb * NHEADS + h) * DK + d)) << 11) + s) = pk;
      } else {
        // Q: fold 1/sqrt(64) * log2(e) so softmax runs in exp2 domain
        const float sc = (mode == 0) ? 0.18033688f : 1.0f;
#pragma unroll
        for (int j = 0; j < 4; ++j) {
          const int rg = rb + j;
          const int bb = rg >> 11, s = rg & 2047;
          dst[((size_t)(bb * NHEADS + h) * SEQ + s) * DK + d] = f2bf((acc[mi][ni][j] + bv) * sc);
        }
      }
    }
  }
}

__global__ __launch_bounds__(512) void gemm_out(const unsigned short* __restrict__ A,
                                                const unsigned short* __restrict__ W,
                                                const float* __restrict__ bias,
                                                float* __restrict__ out) {
  __shared__ __align__(16) unsigned short As[4096];
  __shared__ __align__(16) unsigned short Bs[4096];
  const int m0 = blockIdx.y * 128, n0 = blockIdx.x * 128;
  f32x4 acc[4][2] = {};
  gemm_core(A, W, As, Bs, m0, n0, acc);
  const int lane = threadIdx.x & 63, w = threadIdx.x >> 6;
  const int wr = w >> 2, wc = w & 3;
  const int lr = lane >> 4, lc = lane & 15;
#pragma unroll
  for (int mi = 0; mi < 4; ++mi)
#pragma unroll
    for (int ni = 0; ni < 2; ++ni) {
      const int cg = n0 + wc * 32 + ni * 16 + lc;
      const int rb = m0 + wr * 64 + mi * 16 + lr * 4;
      const float bv = bias[cg];
#pragma unroll
      for (int j = 0; j < 4; ++j)
        out[(size_t)(rb + j) * DMODEL + cg] = acc[mi][ni][j] + bv;
    }
}

// Flash attention, swapped QK^T, exp2-domain softmax, defer-max, dual-tile pipeline.
__global__ __launch_bounds__(256) void attn_fwd(const unsigned short* __restrict__ Qh,
                                                const unsigned short* __restrict__ Kh,
                                                const unsigned short* __restrict__ Vt,
                                                unsigned short* __restrict__ Oh) {
  // per-wave P tile: 16 rows, stride 76 shorts (152 B) -> ~2-way banks on b64 ops
  __shared__ __align__(16) unsigned short P[4][16][76];
  const int t = threadIdx.x, w = t >> 6, lane = t & 63;
  const int bh = blockIdx.x >> 5, qblk = blockIdx.x & 31;
  const int q0 = qblk * 64 + w * 16;
  const unsigned short* Qp = Qh + (size_t)bh * SEQ * DK;
  const unsigned short* Kp = Kh + (size_t)bh * SEQ * DK;
  const unsigned short* Vp = Vt + (size_t)bh * DK * SEQ;
  const int r = lane & 15, g = lane >> 4;
  char* prow = (char*)&P[w][r][0];

  const short8 qf0 = ldg16(Qp + (size_t)(q0 + r) * DK + g * 8);
  const short8 qf1 = ldg16(Qp + (size_t)(q0 + r) * DK + 32 + g * 8);

  float m_run = -1e30f, l_run = 0.f;
  f32x4 o[4] = {};

  // prologue: score tile 0, then prefetch K(1)
  short8 kc0[4], kc1[4];
#pragma unroll
  for (int nt = 0; nt < 4; ++nt) {
    kc0[nt] = ldg16(Kp + (size_t)(nt * 16 + r) * DK + g * 8);
    kc1[nt] = ldg16(Kp + (size_t)(nt * 16 + r) * DK + 32 + g * 8);
  }
  f32x4 sc[4] = {};
#pragma unroll
  for (int nt = 0; nt < 4; ++nt) {
    sc[nt] = __builtin_amdgcn_mfma_f32_16x16x32_bf16(kc0[nt], qf0, sc[nt], 0, 0, 0);
    sc[nt] = __builtin_amdgcn_mfma_f32_16x16x32_bf16(kc1[nt], qf1, sc[nt], 0, 0, 0);
  }
#pragma unroll
  for (int nt = 0; nt < 4; ++nt) {
    kc0[nt] = ldg16(Kp + (size_t)(64 + nt * 16 + r) * DK + g * 8);
    kc1[nt] = ldg16(Kp + (size_t)(64 + nt * 16 + r) * DK + 32 + g * 8);
  }

  for (int kt = 0; kt < 32; ++kt) {
    const int kv0 = kt * 64;
    // V loads for this tile
    short8 vf0[4], vf1[4];
#pragma unroll
    for (int nt = 0; nt < 4; ++nt) {
      vf0[nt] = ldg16(Vp + (size_t)(nt * 16 + r) * SEQ + kv0 + g * 8);
      vf1[nt] = ldg16(Vp + (size_t)(nt * 16 + r) * SEQ + kv0 + 32 + g * 8);
    }
    // next-tile QK^T (pure MFMA; overlaps the VALU softmax below), then K prefetch
    f32x4 sn[4] = {};
    if (kt < 31) {
#pragma unroll
      for (int nt = 0; nt < 4; ++nt) {
        sn[nt] = __builtin_amdgcn_mfma_f32_16x16x32_bf16(kc0[nt], qf0, sn[nt], 0, 0, 0);
        sn[nt] = __builtin_amdgcn_mfma_f32_16x16x32_bf16(kc1[nt], qf1, sn[nt], 0, 0, 0);
      }
      const int kvn = ((kt + 2) & 31) * 64;
#pragma unroll
      for (int nt = 0; nt < 4; ++nt) {
        kc0[nt] = ldg16(Kp + (size_t)(kvn + nt * 16 + r) * DK + g * 8);
        kc1[nt] = ldg16(Kp + (size_t)(kvn + nt * 16 + r) * DK + 32 + g * 8);
      }
    }
    // softmax on sc (exp2 domain); row q=r spread over 4 g-lanes
    f32x4 pm;
#pragma unroll
    for (int j = 0; j < 4; ++j)
      pm[j] = fmaxf(fmaxf(sc[0][j], sc[1][j]), fmaxf(sc[2][j], sc[3][j]));
    float pmax = fmaxf(fmaxf(pm[0], pm[1]), fmaxf(pm[2], pm[3]));
    pmax = fmaxf(pmax, __shfl_xor(pmax, 16));
    pmax = fmaxf(pmax, __shfl_xor(pmax, 32));
    // defer-max: only rescale when the max grew by > 8 (exp2 domain)
    if (!__all(pmax - m_run <= 8.f)) {
      const float mn = fmaxf(m_run, pmax);
      const float al = exp2_hw(m_run - mn);
      m_run = mn;
      l_run *= al;
      float alj[4];
#pragma unroll
      for (int j = 0; j < 4; ++j) alj[j] = __shfl(al, 4 * g + j, 16);
#pragma unroll
      for (int nt = 0; nt < 4; ++nt)
#pragma unroll
        for (int j = 0; j < 4; ++j) o[nt][j] *= alj[j];
    }
#pragma unroll
    for (int nt = 0; nt < 4; ++nt)
#pragma unroll
      for (int j = 0; j < 4; ++j)
        sc[nt][j] = exp2_hw(sc[nt][j] - m_run);
    f32x4 sum4;
#pragma unroll
    for (int j = 0; j < 4; ++j)
      sum4[j] = (sc[0][j] + sc[1][j]) + (sc[2][j] + sc[3][j]);
    float sum = (sum4[0] + sum4[1]) + (sum4[2] + sum4[3]);
    sum += __shfl_xor(sum, 16);
    sum += __shfl_xor(sum, 32);
    l_run += sum;
    // pack P -> LDS (4x ds_write_b64, ~2-way banks)
#pragma unroll
    for (int nt = 0; nt < 4; ++nt) {
      uint2 pk;
      pk.x = cvtpk_bf16(sc[nt][0], sc[nt][1]);
      pk.y = cvtpk_bf16(sc[nt][2], sc[nt][3]);
      *reinterpret_cast<uint2*>(prow + nt * 32 + g * 8) = pk;
    }
    // read P fragments (4x ds_read_b64; compiler inserts lgkmcnt)
    union { short8 v; unsigned long long q[2]; } u0, u1;
    u0.q[0] = *reinterpret_cast<const unsigned long long*>(prow + g * 16);
    u0.q[1] = *reinterpret_cast<const unsigned long long*>(prow + g * 16 + 8);
    u1.q[0] = *reinterpret_cast<const unsigned long long*>(prow + 64 + g * 16);
    u1.q[1] = *reinterpret_cast<const unsigned long long*>(prow + 64 + g * 16 + 8);
    // PV
#pragma unroll
    for (int nt = 0; nt < 4; ++nt) {
      o[nt] = __builtin_amdgcn_mfma_f32_16x16x32_bf16(u0.v, vf0[nt], o[nt], 0, 0, 0);
      o[nt] = __builtin_amdgcn_mfma_f32_16x16x32_bf16(u1.v, vf1[nt], o[nt], 0, 0, 0);
    }
#pragma unroll
    for (int nt = 0; nt < 4; ++nt) sc[nt] = sn[nt];
  }

  const float inv = 1.f / l_run;
  float invj[4];
#pragma unroll
  for (int j = 0; j < 4; ++j) invj[j] = __shfl(inv, 4 * g + j, 16);
  const size_t ob = ((size_t)((bh >> 4) * SEQ + q0)) * DMODEL + (size_t)(bh & 15) * DK;
#pragma unroll
  for (int nt = 0; nt < 4; ++nt)
#pragma unroll
    for (int j = 0; j < 4; ++j)
      Oh[ob + (size_t)(g * 4 + j) * DMODEL + nt * 16 + r] = f2bf(o[nt][j] * invj[j]);
}

extern "C" void kernel_launch(void* const* d_in, const int* in_sizes, int n_in,
                              void* d_out, int out_size, void* d_ws, size_t ws_size,
                              hipStream_t stream) {
  const float* q   = (const float*)d_in[0];
  const float* k   = (const float*)d_in[1];
  const float* v   = (const float*)d_in[2];
  const float* w_q = (const float*)d_in[3];
  const float* b_q = (const float*)d_in[4];
  const float* w_k = (const float*)d_in[5];
  const float* b_k = (const float*)d_in[6];
  const float* w_v = (const float*)d_in[7];
  const float* b_v = (const float*)d_in[8];
  const float* w_o = (const float*)d_in[9];
  const float* b_o = (const float*)d_in[10];
  float* out = (float*)d_out;
  char* ws = (char*)d_ws;
  const size_t MB = (size_t)1 << 20;
  unsigned short* qc  = (unsigned short*)(ws + 0 * MB);
  unsigned short* kc  = (unsigned short*)(ws + 8 * MB);
  unsigned short* vc  = (unsigned short*)(ws + 16 * MB);
  unsigned short* wqc = (unsigned short*)(ws + 24 * MB);
  unsigned short* wkc = (unsigned short*)(ws + 26 * MB);
  unsigned short* wvc = (unsigned short*)(ws + 28 * MB);
  unsigned short* woc = (unsigned short*)(ws + 30 * MB);
  unsigned short* Qh  = (unsigned short*)(ws + 32 * MB);
  unsigned short* Kh  = (unsigned short*)(ws + 40 * MB);
  unsigned short* Vt  = (unsigned short*)(ws + 48 * MB);
  unsigned short* Oh  = (unsigned short*)(ws + 56 * MB);

  cast_qkv<<<dim3(4096, 3), 256, 0, stream>>>(q, k, v, qc, kc, vc);
  cast_w4<<<dim3(1024, 4), 256, 0, stream>>>(w_q, w_k, w_v, w_o, wqc, wkc, wvc, woc);

  ProjPtrs p;
  p.A0 = qc; p.A1 = kc; p.A2 = vc;
  p.W0 = wqc; p.W1 = wkc; p.W2 = wvc;
  p.bias0 = b_q; p.bias1 = b_k; p.bias2 = b_v;
  p.dst0 = Qh; p.dst1 = Kh; p.dst2 = Vt;
  gemm_proj<<<dim3(8, 32, 3), 512, 0, stream>>>(p);

  attn_fwd<<<1024, 256, 0, stream>>>(Qh, Kh, Vt, Oh);

  gemm_out<<<dim3(8, 32), 512, 0, stream>>>(Oh, woc, b_o, out);
}

// Round 5
// 247.565 us; speedup vs baseline: 2.0296x; 1.6430x over previous
//
#include <hip/hip_runtime.h>

typedef __attribute__((ext_vector_type(8))) short short8;
typedef __attribute__((ext_vector_type(4))) float f32x4;

#define NHEADS 16
#define DK 64
#define SEQ 2048
#define DMODEL 1024

__device__ __forceinline__ unsigned short f2bf(float f) {
  union { float f; unsigned int u; } c; c.f = f;
  unsigned int u = c.u;
  return (unsigned short)((u + 0x7FFFu + ((u >> 16) & 1u)) >> 16);
}

__device__ __forceinline__ float exp2_hw(float x) {
  float y;
  asm("v_exp_f32 %0, %1" : "=v"(y) : "v"(x));
  return y;
}

__device__ __forceinline__ unsigned int cvtpk_bf16(float lo, float hi) {
  unsigned int r;
  asm("v_cvt_pk_bf16_f32 %0, %1, %2" : "=v"(r) : "v"(lo), "v"(hi));
  return r;
}

__device__ __forceinline__ short8 ldg16(const unsigned short* p) {
  return *reinterpret_cast<const short8*>(p);
}

__device__ __forceinline__ void gload_lds16(const unsigned short* g, unsigned short* l) {
  __builtin_amdgcn_global_load_lds(
      (const __attribute__((address_space(1))) unsigned int*)g,
      (__attribute__((address_space(3))) unsigned int*)l, 16, 0, 0);
}

__global__ void cast_qkv(const float* __restrict__ a0, const float* __restrict__ a1,
                         const float* __restrict__ a2, unsigned short* __restrict__ d0,
                         unsigned short* __restrict__ d1, unsigned short* __restrict__ d2) {
  const float* s = blockIdx.y == 0 ? a0 : (blockIdx.y == 1 ? a1 : a2);
  unsigned short* d = blockIdx.y == 0 ? d0 : (blockIdx.y == 1 ? d1 : d2);
  int i = blockIdx.x * blockDim.x + threadIdx.x;
  float4 v = reinterpret_cast<const float4*>(s)[i];
  ushort4 o;
  o.x = f2bf(v.x); o.y = f2bf(v.y); o.z = f2bf(v.z); o.w = f2bf(v.w);
  reinterpret_cast<ushort4*>(d)[i] = o;
}

__global__ void cast_w4(const float* __restrict__ a0, const float* __restrict__ a1,
                        const float* __restrict__ a2, const float* __restrict__ a3,
                        unsigned short* __restrict__ d0, unsigned short* __restrict__ d1,
                        unsigned short* __restrict__ d2, unsigned short* __restrict__ d3) {
  const float* s = blockIdx.y == 0 ? a0 : (blockIdx.y == 1 ? a1 : (blockIdx.y == 2 ? a2 : a3));
  unsigned short* d = blockIdx.y == 0 ? d0 : (blockIdx.y == 1 ? d1 : (blockIdx.y == 2 ? d2 : d3));
  int i = blockIdx.x * blockDim.x + threadIdx.x;
  float4 v = reinterpret_cast<const float4*>(s)[i];
  ushort4 o;
  o.x = f2bf(v.x); o.y = f2bf(v.y); o.z = f2bf(v.z); o.w = f2bf(v.w);
  reinterpret_cast<ushort4*>(d)[i] = o;
}

// ---- 128x128-tile GEMM core, 8 waves (512 thr), wave tile 64x32.
__device__ __forceinline__ void gemm_core(const unsigned short* __restrict__ A,
                                          const unsigned short* __restrict__ W,
                                          unsigned short* As, unsigned short* Bs,
                                          int m0, int n0, f32x4 acc[4][2]) {
  const int t = threadIdx.x;
  const int lane = t & 63, w = t >> 6;
  const int wr = w >> 2, wc = w & 3;
  const int srow = t >> 2, scol = (t & 3) * 8;
  const int lr = lane >> 4, lc = lane & 15;
  for (int k0 = 0; k0 < DMODEL; k0 += 32) {
    __syncthreads();
    gload_lds16(A + (size_t)(m0 + srow) * DMODEL + k0 + scol, As + w * 512);
    gload_lds16(W + (size_t)(n0 + srow) * DMODEL + k0 + scol, Bs + w * 512);
    __syncthreads();
    short8 a[4], b[2];
#pragma unroll
    for (int i = 0; i < 4; ++i)
      a[i] = *reinterpret_cast<const short8*>(As + (wr * 64 + i * 16 + lc) * 32 + lr * 8);
#pragma unroll
    for (int i = 0; i < 2; ++i)
      b[i] = *reinterpret_cast<const short8*>(Bs + (wc * 32 + i * 16 + lc) * 32 + lr * 8);
#pragma unroll
    for (int mi = 0; mi < 4; ++mi)
#pragma unroll
      for (int ni = 0; ni < 2; ++ni)
        acc[mi][ni] = __builtin_amdgcn_mfma_f32_16x16x32_bf16(a[mi], b[ni], acc[mi][ni], 0, 0, 0);
  }
}

struct ProjPtrs {
  const unsigned short* A0; const unsigned short* A1; const unsigned short* A2;
  const unsigned short* W0; const unsigned short* W1; const unsigned short* W2;
  const float* bias0; const float* bias1; const float* bias2;
  unsigned short* dst0; unsigned short* dst1; unsigned short* dst2;
};

// z=0: Q (pre-scaled 1/8*log2e, [B,H,S,64]); z=1: K; z=2: V transposed ([B,H,64,S])
__global__ __launch_bounds__(512) void gemm_proj(ProjPtrs p) {
  __shared__ __align__(16) unsigned short As[4096];
  __shared__ __align__(16) unsigned short Bs[4096];
  const int mode = blockIdx.z;
  const unsigned short* A = mode == 0 ? p.A0 : (mode == 1 ? p.A1 : p.A2);
  const unsigned short* W = mode == 0 ? p.W0 : (mode == 1 ? p.W1 : p.W2);
  const float* bias = mode == 0 ? p.bias0 : (mode == 1 ? p.bias1 : p.bias2);
  unsigned short* dst = mode == 0 ? p.dst0 : (mode == 1 ? p.dst1 : p.dst2);
  const int m0 = blockIdx.y * 128, n0 = blockIdx.x * 128;
  f32x4 acc[4][2] = {};
  gemm_core(A, W, As, Bs, m0, n0, acc);
  const int lane = threadIdx.x & 63, w = threadIdx.x >> 6;
  const int wr = w >> 2, wc = w & 3;
  const int lr = lane >> 4, lc = lane & 15;
#pragma unroll
  for (int mi = 0; mi < 4; ++mi) {
#pragma unroll
    for (int ni = 0; ni < 2; ++ni) {
      const int cg = n0 + wc * 32 + ni * 16 + lc;
      const int rb = m0 + wr * 64 + mi * 16 + lr * 4;
      const float bv = bias[cg];
      const int h = cg >> 6, d = cg & 63;
      if (mode == 2) {
        const int bb = rb >> 11, s = rb & 2047;
        ushort4 pk;
        pk.x = f2bf(acc[mi][ni][0] + bv);
        pk.y = f2bf(acc[mi][ni][1] + bv);
        pk.z = f2bf(acc[mi][ni][2] + bv);
        pk.w = f2bf(acc[mi][ni][3] + bv);
        *reinterpret_cast<ushort4*>(dst + (((size_t)((bb * NHEADS + h) * DK + d)) << 11) + s) = pk;
      } else {
        // Q: fold 1/sqrt(64) * log2(e) so softmax runs in exp2 domain
        const float sc = (mode == 0) ? 0.18033688f : 1.0f;
#pragma unroll
        for (int j = 0; j < 4; ++j) {
          const int rg = rb + j;
          const int bb = rg >> 11, s = rg & 2047;
          dst[((size_t)(bb * NHEADS + h) * SEQ + s) * DK + d] = f2bf((acc[mi][ni][j] + bv) * sc);
        }
      }
    }
  }
}

__global__ __launch_bounds__(512) void gemm_out(const unsigned short* __restrict__ A,
                                                const unsigned short* __restrict__ W,
                                                const float* __restrict__ bias,
                                                float* __restrict__ out) {
  __shared__ __align__(16) unsigned short As[4096];
  __shared__ __align__(16) unsigned short Bs[4096];
  const int m0 = blockIdx.y * 128, n0 = blockIdx.x * 128;
  f32x4 acc[4][2] = {};
  gemm_core(A, W, As, Bs, m0, n0, acc);
  const int lane = threadIdx.x & 63, w = threadIdx.x >> 6;
  const int wr = w >> 2, wc = w & 3;
  const int lr = lane >> 4, lc = lane & 15;
#pragma unroll
  for (int mi = 0; mi < 4; ++mi)
#pragma unroll
    for (int ni = 0; ni < 2; ++ni) {
      const int cg = n0 + wc * 32 + ni * 16 + lc;
      const int rb = m0 + wr * 64 + mi * 16 + lr * 4;
      const float bv = bias[cg];
#pragma unroll
      for (int j = 0; j < 4; ++j)
        out[(size_t)(rb + j) * DMODEL + cg] = acc[mi][ni][j] + bv;
    }
}

// Flash attention: 4 waves/block, 32 q-rows/wave (two 16-row halves), K/V tiles
// double-buffered in LDS via global_load_lds with XOR-swizzle (slot ^= row&7).
__global__ __launch_bounds__(256) void attn_fwd(const unsigned short* __restrict__ Qh,
                                                const unsigned short* __restrict__ Kh,
                                                const unsigned short* __restrict__ Vt,
                                                unsigned short* __restrict__ Oh) {
  __shared__ __align__(16) unsigned short Ktile[2][4096];   // [kv 64][d 64], swizzled
  __shared__ __align__(16) unsigned short Vtile[2][4096];   // [d 64][kv 64], swizzled
  __shared__ __align__(16) unsigned short P[4][32][76];     // per-wave [q][kv], padded
  const int t = threadIdx.x, w = t >> 6, lane = t & 63;
  // XCD swizzle (512 blocks, 8 XCDs): blocks sharing (b,h) land on one XCD's L2
  const int bx = ((blockIdx.x & 7) << 6) | (blockIdx.x >> 3);
  const int bh = bx >> 4, qblk = bx & 15;
  const int q0 = qblk * 128 + w * 32;
  const unsigned short* Qp = Qh + (size_t)bh * SEQ * DK;
  const unsigned short* Kp = Kh + (size_t)bh * SEQ * DK;
  const unsigned short* Vp = Vt + (size_t)bh * DK * SEQ;
  const int r = lane & 15, g = lane >> 4;

  // Q fragments (B-operand): halves A (rows q0..+15) and B (rows q0+16..+31)
  const short8 qa0 = ldg16(Qp + (size_t)(q0 + r) * DK + g * 8);
  const short8 qa1 = ldg16(Qp + (size_t)(q0 + r) * DK + 32 + g * 8);
  const short8 qb0 = ldg16(Qp + (size_t)(q0 + 16 + r) * DK + g * 8);
  const short8 qb1 = ldg16(Qp + (size_t)(q0 + 16 + r) * DK + 32 + g * 8);

  // staging: 512 chunks of 16B per tile; this thread owns chunks c0, c1.
  // LDS linear chunk c = row*8 + slot; source slot = slot ^ (row&7).
  const int c0 = w * 64 + lane, c1 = c0 + 256;
  const int r0 = c0 >> 3, s0 = (c0 & 7) ^ (r0 & 7);
  const int r1 = c1 >> 3, s1 = (c1 & 7) ^ (r1 & 7);
  const unsigned short* ks0 = Kp + r0 * DK + s0 * 8;
  const unsigned short* ks1 = Kp + r1 * DK + s1 * 8;
  const unsigned short* vs0 = Vp + (size_t)r0 * SEQ + s0 * 8;
  const unsigned short* vs1 = Vp + (size_t)r1 * SEQ + s1 * 8;

  float mA = -1e30f, lA = 0.f, mB = -1e30f, lB = 0.f;
  f32x4 oA[4] = {}, oB[4] = {};

  // swizzled read offsets (shorts): k-chunk g -> slot g^(r&7); chunk g+4 -> (g+4)^(r&7)
  const int sw0 = ((g ^ (r & 7)) << 3);
  const int sw1 = (((g + 4) ^ (r & 7)) << 3);
  char* prowA = (char*)&P[w][r][0];
  char* prowB = (char*)&P[w][16 + r][0];

  // prologue: stage tile 0 into buf 0
  gload_lds16(ks0, &Ktile[0][w * 512]);
  gload_lds16(ks1, &Ktile[0][2048 + w * 512]);
  gload_lds16(vs0, &Vtile[0][w * 512]);
  gload_lds16(vs1, &Vtile[0][2048 + w * 512]);
  __syncthreads();

  int buf = 0;
  for (int kt = 0; kt < 32; ++kt) {
    // issue next-tile staging (drained by the barrier at end of this iter)
    if (kt < 31) {
      const int kvn = (kt + 1) * 64;
      gload_lds16(ks0 + kvn * DK, &Ktile[buf ^ 1][w * 512]);
      gload_lds16(ks1 + kvn * DK, &Ktile[buf ^ 1][2048 + w * 512]);
      gload_lds16(vs0 + kvn, &Vtile[buf ^ 1][w * 512]);
      gload_lds16(vs1 + kvn, &Vtile[buf ^ 1][2048 + w * 512]);
    }
    // K fragments from LDS; QK^T swapped: D[kv][q], lane holds q=r, kv=16nt+4g+j
    f32x4 sA[4] = {}, sB[4] = {};
#pragma unroll
    for (int nt = 0; nt < 4; ++nt) {
      const short8 k0 = *reinterpret_cast<const short8*>(&Ktile[buf][(nt * 16 + r) * 64 + sw0]);
      const short8 k1 = *reinterpret_cast<const short8*>(&Ktile[buf][(nt * 16 + r) * 64 + sw1]);
      sA[nt] = __builtin_amdgcn_mfma_f32_16x16x32_bf16(k0, qa0, sA[nt], 0, 0, 0);
      sA[nt] = __builtin_amdgcn_mfma_f32_16x16x32_bf16(k1, qa1, sA[nt], 0, 0, 0);
      sB[nt] = __builtin_amdgcn_mfma_f32_16x16x32_bf16(k0, qb0, sB[nt], 0, 0, 0);
      sB[nt] = __builtin_amdgcn_mfma_f32_16x16x32_bf16(k1, qb1, sB[nt], 0, 0, 0);
    }
    // softmax half A (exp2 domain, defer-max THR=8)
    {
      f32x4 pm;
#pragma unroll
      for (int j = 0; j < 4; ++j)
        pm[j] = fmaxf(fmaxf(sA[0][j], sA[1][j]), fmaxf(sA[2][j], sA[3][j]));
      float pmax = fmaxf(fmaxf(pm[0], pm[1]), fmaxf(pm[2], pm[3]));
      pmax = fmaxf(pmax, __shfl_xor(pmax, 16));
      pmax = fmaxf(pmax, __shfl_xor(pmax, 32));
      if (!__all(pmax - mA <= 8.f)) {
        const float mn = fmaxf(mA, pmax);
        const float al = exp2_hw(mA - mn);
        mA = mn; lA *= al;
        float alj[4];
#pragma unroll
        for (int j = 0; j < 4; ++j) alj[j] = __shfl(al, 4 * g + j, 16);
#pragma unroll
        for (int nt = 0; nt < 4; ++nt)
#pragma unroll
          for (int j = 0; j < 4; ++j) oA[nt][j] *= alj[j];
      }
#pragma unroll
      for (int nt = 0; nt < 4; ++nt)
#pragma unroll
        for (int j = 0; j < 4; ++j) sA[nt][j] = exp2_hw(sA[nt][j] - mA);
      f32x4 s4;
#pragma unroll
      for (int j = 0; j < 4; ++j) s4[j] = (sA[0][j] + sA[1][j]) + (sA[2][j] + sA[3][j]);
      float sum = (s4[0] + s4[1]) + (s4[2] + s4[3]);
      sum += __shfl_xor(sum, 16);
      sum += __shfl_xor(sum, 32);
      lA += sum;
#pragma unroll
      for (int nt = 0; nt < 4; ++nt) {
        uint2 pk;
        pk.x = cvtpk_bf16(sA[nt][0], sA[nt][1]);
        pk.y = cvtpk_bf16(sA[nt][2], sA[nt][3]);
        *reinterpret_cast<uint2*>(prowA + nt * 32 + g * 8) = pk;
      }
    }
    // softmax half B
    {
      f32x4 pm;
#pragma unroll
      for (int j = 0; j < 4; ++j)
        pm[j] = fmaxf(fmaxf(sB[0][j], sB[1][j]), fmaxf(sB[2][j], sB[3][j]));
      float pmax = fmaxf(fmaxf(pm[0], pm[1]), fmaxf(pm[2], pm[3]));
      pmax = fmaxf(pmax, __shfl_xor(pmax, 16));
      pmax = fmaxf(pmax, __shfl_xor(pmax, 32));
      if (!__all(pmax - mB <= 8.f)) {
        const float mn = fmaxf(mB, pmax);
        const float al = exp2_hw(mB - mn);
        mB = mn; lB *= al;
        float alj[4];
#pragma unroll
        for (int j = 0; j < 4; ++j) alj[j] = __shfl(al, 4 * g + j, 16);
#pragma unroll
        for (int nt = 0; nt < 4; ++nt)
#pragma unroll
          for (int j = 0; j < 4; ++j) oB[nt][j] *= alj[j];
      }
#pragma unroll
      for (int nt = 0; nt < 4; ++nt)
#pragma unroll
        for (int j = 0; j < 4; ++j) sB[nt][j] = exp2_hw(sB[nt][j] - mB);
      f32x4 s4;
#pragma unroll
      for (int j = 0; j < 4; ++j) s4[j] = (sB[0][j] + sB[1][j]) + (sB[2][j] + sB[3][j]);
      float sum = (s4[0] + s4[1]) + (s4[2] + s4[3]);
      sum += __shfl_xor(sum, 16);
      sum += __shfl_xor(sum, 32);
      lB += sum;
#pragma unroll
      for (int nt = 0; nt < 4; ++nt) {
        uint2 pk;
        pk.x = cvtpk_bf16(sB[nt][0], sB[nt][1]);
        pk.y = cvtpk_bf16(sB[nt][2], sB[nt][3]);
        *reinterpret_cast<uint2*>(prowB + nt * 32 + g * 8) = pk;
      }
    }
    // P fragments (per-wave LDS; compiler inserts lgkmcnt)
    union { short8 v; unsigned long long q[2]; } pA0, pA1, pB0, pB1;
    pA0.q[0] = *reinterpret_cast<const unsigned long long*>(prowA + g * 16);
    pA0.q[1] = *reinterpret_cast<const unsigned long long*>(prowA + g * 16 + 8);
    pA1.q[0] = *reinterpret_cast<const unsigned long long*>(prowA + 64 + g * 16);
    pA1.q[1] = *reinterpret_cast<const unsigned long long*>(prowA + 64 + g * 16 + 8);
    pB0.q[0] = *reinterpret_cast<const unsigned long long*>(prowB + g * 16);
    pB0.q[1] = *reinterpret_cast<const unsigned long long*>(prowB + g * 16 + 8);
    pB1.q[0] = *reinterpret_cast<const unsigned long long*>(prowB + 64 + g * 16);
    pB1.q[1] = *reinterpret_cast<const unsigned long long*>(prowB + 64 + g * 16 + 8);
    // V fragments + PV
#pragma unroll
    for (int nt = 0; nt < 4; ++nt) {
      const short8 v0 = *reinterpret_cast<const short8*>(&Vtile[buf][(nt * 16 + r) * 64 + sw0]);
      const short8 v1 = *reinterpret_cast<const short8*>(&Vtile[buf][(nt * 16 + r) * 64 + sw1]);
      oA[nt] = __builtin_amdgcn_mfma_f32_16x16x32_bf16(pA0.v, v0, oA[nt], 0, 0, 0);
      oA[nt] = __builtin_amdgcn_mfma_f32_16x16x32_bf16(pA1.v, v1, oA[nt], 0, 0, 0);
      oB[nt] = __builtin_amdgcn_mfma_f32_16x16x32_bf16(pB0.v, v0, oB[nt], 0, 0, 0);
      oB[nt] = __builtin_amdgcn_mfma_f32_16x16x32_bf16(pB1.v, v1, oB[nt], 0, 0, 0);
    }
    __syncthreads();  // drains next-tile staging (vmcnt) + protects buffer swap
    buf ^= 1;
  }

  const float invA = 1.f / lA, invB = 1.f / lB;
  float ivA[4], ivB[4];
#pragma unroll
  for (int j = 0; j < 4; ++j) {
    ivA[j] = __shfl(invA, 4 * g + j, 16);
    ivB[j] = __shfl(invB, 4 * g + j, 16);
  }
  const size_t ob = ((size_t)((bh >> 4) * SEQ + q0)) * DMODEL + (size_t)(bh & 15) * DK;
#pragma unroll
  for (int nt = 0; nt < 4; ++nt)
#pragma unroll
    for (int j = 0; j < 4; ++j) {
      Oh[ob + (size_t)(g * 4 + j) * DMODEL + nt * 16 + r] = f2bf(oA[nt][j] * ivA[j]);
      Oh[ob + (size_t)(16 + g * 4 + j) * DMODEL + nt * 16 + r] = f2bf(oB[nt][j] * ivB[j]);
    }
}

extern "C" void kernel_launch(void* const* d_in, const int* in_sizes, int n_in,
                              void* d_out, int out_size, void* d_ws, size_t ws_size,
                              hipStream_t stream) {
  const float* q   = (const float*)d_in[0];
  const float* k   = (const float*)d_in[1];
  const float* v   = (const float*)d_in[2];
  const float* w_q = (const float*)d_in[3];
  const float* b_q = (const float*)d_in[4];
  const float* w_k = (const float*)d_in[5];
  const float* b_k = (const float*)d_in[6];
  const float* w_v = (const float*)d_in[7];
  const float* b_v = (const float*)d_in[8];
  const float* w_o = (const float*)d_in[9];
  const float* b_o = (const float*)d_in[10];
  float* out = (float*)d_out;
  char* ws = (char*)d_ws;
  const size_t MB = (size_t)1 << 20;
  unsigned short* qc  = (unsigned short*)(ws + 0 * MB);
  unsigned short* kc  = (unsigned short*)(ws + 8 * MB);
  unsigned short* vc  = (unsigned short*)(ws + 16 * MB);
  unsigned short* wqc = (unsigned short*)(ws + 24 * MB);
  unsigned short* wkc = (unsigned short*)(ws + 26 * MB);
  unsigned short* wvc = (unsigned short*)(ws + 28 * MB);
  unsigned short* woc = (unsigned short*)(ws + 30 * MB);
  unsigned short* Qh  = (unsigned short*)(ws + 32 * MB);
  unsigned short* Kh  = (unsigned short*)(ws + 40 * MB);
  unsigned short* Vt  = (unsigned short*)(ws + 48 * MB);
  unsigned short* Oh  = (unsigned short*)(ws + 56 * MB);

  cast_qkv<<<dim3(4096, 3), 256, 0, stream>>>(q, k, v, qc, kc, vc);
  cast_w4<<<dim3(1024, 4), 256, 0, stream>>>(w_q, w_k, w_v, w_o, wqc, wkc, wvc, woc);

  ProjPtrs p;
  p.A0 = qc; p.A1 = kc; p.A2 = vc;
  p.W0 = wqc; p.W1 = wkc; p.W2 = wvc;
  p.bias0 = b_q; p.bias1 = b_k; p.bias2 = b_v;
  p.dst0 = Qh; p.dst1 = Kh; p.dst2 = Vt;
  gemm_proj<<<dim3(8, 32, 3), 512, 0, stream>>>(p);

  attn_fwd<<<512, 256, 0, stream>>>(Qh, Kh, Vt, Oh);

  gemm_out<<<dim3(8, 32), 512, 0, stream>>>(Oh, woc, b_o, out);
}